// Round 3
// baseline (459.587 us; speedup 1.0000x reference)
//
#include <hip/hip_runtime.h>
#include <hip/hip_bf16.h>

#define D 512
#define D4 (D / 4)
#define ND 4
#define EPSF 1e-3f
#define SROWS 32  // rows per block in stats/norm kernels

// ---------------------------------------------------------------------------
// Kernel A: per-row domain id (argmax of one-hot, first-max-wins) + counts.
// ---------------------------------------------------------------------------
__global__ __launch_bounds__(256) void dom_kernel(const float4* __restrict__ ind,
                                                  unsigned char* __restrict__ dom,
                                                  float* __restrict__ cnt, int B) {
  __shared__ int lc[ND];
  const int t = threadIdx.x;
  if (t < ND) lc[t] = 0;
  __syncthreads();
  const int i = blockIdx.x * blockDim.x + t;
  if (i < B) {
    float4 v = ind[i];  // coalesced: thread i reads floats [4i, 4i+4)
    int d = 0;
    float best = v.x;
    if (v.y > best) { best = v.y; d = 1; }
    if (v.z > best) { best = v.z; d = 2; }
    if (v.w > best) { best = v.w; d = 3; }
    dom[i] = (unsigned char)d;
    atomicAdd(&lc[d], 1);
  }
  __syncthreads();
  if (t < ND && lc[t]) atomicAdd(&cnt[t], (float)lc[t]);
}

// Select the dom word for compile-time even byte index 'bi' (bi and bi+1 are
// always in the same 32-bit word since bi is even).
#define DOMW(bi)                                                               \
  ((bi) < 4 ? dva.x : (bi) < 8 ? dva.y : (bi) < 12 ? dva.z : (bi) < 16         \
   ? dva.w : (bi) < 20 ? dvb.x : (bi) < 24 ? dvb.y : (bi) < 28 ? dvb.z : dvb.w)
#define DOMB(bi) ((int)((DOMW(bi) >> (8 * ((bi) & 3) + rsh)) & 3))

// ---------------------------------------------------------------------------
// Kernel B: per-domain per-column sum & sqsum.
// 2048 blocks x 256 thr; thread owns cols [tc*4,tc*4+4), row-group rg=t>>7.
// dom bytes preloaded as 2x uint4 (static word index, runtime shift only);
// 4 independent float4 loads in flight per unrolled step (MLP).
// ---------------------------------------------------------------------------
__global__ __launch_bounds__(256) void stats_kernel(const float4* __restrict__ x,
                                                    const unsigned char* __restrict__ dom,
                                                    float* __restrict__ sums,
                                                    float* __restrict__ sqs, int B) {
  const int t = threadIdx.x;
  const int tc = t & 127;
  const int rg = t >> 7;
  const int base = blockIdx.x * SROWS;
  const int rsh = 8 * rg;  // wave-uniform extra byte shift

  float s[ND][4] = {};
  float q[ND][4] = {};

#define ACC(dd, v)                                                             \
  do {                                                                         \
    s[dd][0] += (v).x; s[dd][1] += (v).y; s[dd][2] += (v).z; s[dd][3] += (v).w;\
    q[dd][0] += (v).x * (v).x; q[dd][1] += (v).y * (v).y;                      \
    q[dd][2] += (v).z * (v).z; q[dd][3] += (v).w * (v).w;                      \
  } while (0)
#define ROWACC(v, d)                                                           \
  do {                                                                         \
    const int _d = (d); /* wave-uniform: whole wave shares the row */          \
    if (_d == 0) ACC(0, v);                                                    \
    else if (_d == 1) ACC(1, v);                                               \
    else if (_d == 2) ACC(2, v);                                               \
    else ACC(3, v);                                                            \
  } while (0)

  if (base + SROWS <= B) {
    const uint4* dp = (const uint4*)(dom + base);
    const uint4 dva = dp[0];
    const uint4 dvb = dp[1];
    const float4* xp = x + (size_t)(base + rg) * D4 + tc;
#pragma unroll
    for (int it = 0; it < SROWS; it += 8) {
      float4 v0 = xp[(size_t)(it + 0) * D4];
      float4 v1 = xp[(size_t)(it + 2) * D4];
      float4 v2 = xp[(size_t)(it + 4) * D4];
      float4 v3 = xp[(size_t)(it + 6) * D4];
      const int d0 = DOMB(it + 0);
      const int d1 = DOMB(it + 2);
      const int d2 = DOMB(it + 4);
      const int d3 = DOMB(it + 6);
      ROWACC(v0, d0);
      ROWACC(v1, d1);
      ROWACC(v2, d2);
      ROWACC(v3, d3);
    }
  } else {  // tail block (not hit when B % SROWS == 0)
    for (int it = 0; it < SROWS; it += 2) {
      const int r = base + it + rg;
      if (r < B) {
        const int d = dom[r];
        float4 v = x[(size_t)r * D4 + tc];
        ROWACC(v, d);
      }
    }
  }

  // Cross-row-group reduce via LDS (stride 33 floats: conflict-free),
  // then split the 4096 atomics across both row-groups.
  __shared__ float red[128 * 33];
  if (rg == 1) {
#pragma unroll
    for (int dd = 0; dd < ND; ++dd)
#pragma unroll
      for (int c = 0; c < 4; ++c) red[tc * 33 + dd * 4 + c] = s[dd][c];
  } else {
#pragma unroll
    for (int dd = 0; dd < ND; ++dd)
#pragma unroll
      for (int c = 0; c < 4; ++c) red[tc * 33 + 16 + dd * 4 + c] = q[dd][c];
  }
  __syncthreads();
  if (rg == 0) {
#pragma unroll
    for (int dd = 0; dd < ND; ++dd)
#pragma unroll
      for (int c = 0; c < 4; ++c)
        atomicAdd(&sums[dd * D + tc * 4 + c], s[dd][c] + red[tc * 33 + dd * 4 + c]);
  } else {
#pragma unroll
    for (int dd = 0; dd < ND; ++dd)
#pragma unroll
      for (int c = 0; c < 4; ++c)
        atomicAdd(&sqs[dd * D + tc * 4 + c], q[dd][c] + red[tc * 33 + 16 + dd * 4 + c]);
  }
}

// ---------------------------------------------------------------------------
// Kernel C: finalize -> inv = gamma * rsqrt(var + eps), shift = beta - mean*inv.
// ---------------------------------------------------------------------------
__global__ __launch_bounds__(256) void fin_kernel(const float* __restrict__ sums,
                                                  const float* __restrict__ sqs,
                                                  const float* __restrict__ cnt,
                                                  const float* __restrict__ gamma,
                                                  const float* __restrict__ beta,
                                                  float* __restrict__ inv,
                                                  float* __restrict__ shf) {
  const int i = blockIdx.x * blockDim.x + threadIdx.x;
  if (i < ND * D) {
    const int d = i >> 9;  // /512
    const float c = fmaxf(cnt[d], 1.0f);
    const float m = sums[i] / c;
    const float va = sqs[i] / c - m * m;  // biased variance
    const float iv = gamma[i] * rsqrtf(va + EPSF);
    inv[i] = iv;
    shf[i] = beta[i] - m * iv;
  }
}

// ---------------------------------------------------------------------------
// Kernel D: out = fma(x, inv[dom], shift[dom]).
// All 4 domains' (inv,shf) float4s for this thread's columns live in registers
// (32 VGPRs); wave-uniform branch selects. Loop is a pure stream.
// ---------------------------------------------------------------------------
__global__ __launch_bounds__(256) void norm_kernel(const float4* __restrict__ x,
                                                   const unsigned char* __restrict__ dom,
                                                   const float4* __restrict__ inv,
                                                   const float4* __restrict__ shf,
                                                   float4* __restrict__ out, int B) {
  const int t = threadIdx.x;
  const int tc = t & 127;
  const int rg = t >> 7;
  const int base = blockIdx.x * SROWS;
  const int rsh = 8 * rg;

  const float4 A0 = inv[0 * D4 + tc], A1 = inv[1 * D4 + tc];
  const float4 A2 = inv[2 * D4 + tc], A3 = inv[3 * D4 + tc];
  const float4 B0 = shf[0 * D4 + tc], B1 = shf[1 * D4 + tc];
  const float4 B2 = shf[2 * D4 + tc], B3 = shf[3 * D4 + tc];

#define NROW(v, d, ptr)                                                        \
  do {                                                                         \
    const int _d = (d);                                                        \
    float4 a, b;                                                               \
    if (_d == 0) { a = A0; b = B0; }                                           \
    else if (_d == 1) { a = A1; b = B1; }                                      \
    else if (_d == 2) { a = A2; b = B2; }                                      \
    else { a = A3; b = B3; }                                                   \
    float4 o;                                                                  \
    o.x = fmaf((v).x, a.x, b.x); o.y = fmaf((v).y, a.y, b.y);                  \
    o.z = fmaf((v).z, a.z, b.z); o.w = fmaf((v).w, a.w, b.w);                  \
    *(ptr) = o;                                                                \
  } while (0)

  if (base + SROWS <= B) {
    const uint4* dp = (const uint4*)(dom + base);
    const uint4 dva = dp[0];
    const uint4 dvb = dp[1];
    const float4* xp = x + (size_t)(base + rg) * D4 + tc;
    float4* op = out + (size_t)(base + rg) * D4 + tc;
#pragma unroll
    for (int it = 0; it < SROWS; it += 8) {
      float4 v0 = xp[(size_t)(it + 0) * D4];
      float4 v1 = xp[(size_t)(it + 2) * D4];
      float4 v2 = xp[(size_t)(it + 4) * D4];
      float4 v3 = xp[(size_t)(it + 6) * D4];
      const int d0 = DOMB(it + 0);
      const int d1 = DOMB(it + 2);
      const int d2 = DOMB(it + 4);
      const int d3 = DOMB(it + 6);
      NROW(v0, d0, op + (size_t)(it + 0) * D4);
      NROW(v1, d1, op + (size_t)(it + 2) * D4);
      NROW(v2, d2, op + (size_t)(it + 4) * D4);
      NROW(v3, d3, op + (size_t)(it + 6) * D4);
    }
  } else {  // tail block
    for (int it = 0; it < SROWS; it += 2) {
      const int r = base + it + rg;
      if (r < B) {
        const int d = dom[r];
        float4 v = x[(size_t)r * D4 + tc];
        NROW(v, d, out + (size_t)r * D4 + tc);
      }
    }
  }
}

extern "C" void kernel_launch(void* const* d_in, const int* in_sizes, int n_in,
                              void* d_out, int out_size, void* d_ws, size_t ws_size,
                              hipStream_t stream) {
  const float* x = (const float*)d_in[0];
  const float* ind = (const float*)d_in[1];
  const float* gamma = (const float*)d_in[2];
  const float* beta = (const float*)d_in[3];
  float* out = (float*)d_out;
  const int B = in_sizes[0] / D;

  // Workspace layout (bytes):
  //   [0,16)        cnt[ND]
  //   [256,8448)    sums[ND*D]
  //   [8448,16640)  sqs[ND*D]
  //   [16640,24832) inv[ND*D]
  //   [24832,33024) shf[ND*D]
  //   [33024,...)   dom[B] uint8
  char* ws = (char*)d_ws;
  float* cnt = (float*)(ws + 0);
  float* sums = (float*)(ws + 256);
  float* sqs = (float*)(ws + 256 + 8192);
  float* inv = (float*)(ws + 256 + 16384);
  float* shf = (float*)(ws + 256 + 24576);
  unsigned char* dom = (unsigned char*)(ws + 256 + 32768);

  // Accumulators must start at zero (ws is poisoned 0xAA before every call).
  (void)hipMemsetAsync(d_ws, 0, 256 + 16384, stream);

  dom_kernel<<<(B + 255) / 256, 256, 0, stream>>>((const float4*)ind, dom, cnt, B);

  const int nblk = (B + SROWS - 1) / SROWS;  // 2048 at B=65536 -> 8 blocks/CU
  stats_kernel<<<nblk, 256, 0, stream>>>((const float4*)x, dom, sums, sqs, B);

  fin_kernel<<<(ND * D + 255) / 256, 256, 0, stream>>>(sums, sqs, cnt, gamma, beta,
                                                       inv, shf);

  norm_kernel<<<nblk, 256, 0, stream>>>((const float4*)x, dom, (const float4*)inv,
                                        (const float4*)shf, (float4*)out, B);
}

// Round 4
// 320.690 us; speedup vs baseline: 1.4331x; 1.4331x over previous
//
#include <hip/hip_runtime.h>
#include <hip/hip_bf16.h>

#define D 512
#define D4 (D / 4)
#define ND 4
#define EPSF 1e-3f
#define SROWS 128  // rows per stats block -> 512 blocks at B=65536
#define NROWS 32   // rows per norm block  -> 2048 blocks

// ---------------------------------------------------------------------------
// Kernel A: per-row domain id (argmax of one-hot, first-max-wins) + counts.
// ---------------------------------------------------------------------------
__global__ __launch_bounds__(256) void dom_kernel(const float4* __restrict__ ind,
                                                  unsigned char* __restrict__ dom,
                                                  float* __restrict__ cnt, int B) {
  __shared__ int lc[ND];
  const int t = threadIdx.x;
  if (t < ND) lc[t] = 0;
  __syncthreads();
  const int i = blockIdx.x * blockDim.x + t;
  if (i < B) {
    float4 v = ind[i];
    int d = 0;
    float best = v.x;
    if (v.y > best) { best = v.y; d = 1; }
    if (v.z > best) { best = v.z; d = 2; }
    if (v.w > best) { best = v.w; d = 3; }
    dom[i] = (unsigned char)d;
    atomicAdd(&lc[d], 1);
  }
  __syncthreads();
  if (t < ND && lc[t]) atomicAdd(&cnt[t], (float)lc[t]);
}

// Pick the dom word for compile-time even byte index bi within a 32-byte chunk
// held in named uint4s dva/dvb; actual row byte = bi + rg, handled by rsh.
#define DOMW(bi)                                                               \
  ((bi) < 4 ? dva.x : (bi) < 8 ? dva.y : (bi) < 12 ? dva.z : (bi) < 16         \
   ? dva.w : (bi) < 20 ? dvb.x : (bi) < 24 ? dvb.y : (bi) < 28 ? dvb.z : dvb.w)
#define DOMB(bi)                                                               \
  __builtin_amdgcn_readfirstlane((int)((DOMW(bi) >> (8 * ((bi) & 3) + rsh)) & 3))

// ---------------------------------------------------------------------------
// Kernel B: per-domain per-column sum & sqsum.
// NAMED float4 accumulators only (no arrays -> nothing can go to scratch).
// Thread owns cols [tc*4,tc*4+4); row-group rg = t>>7 takes odd/even rows.
// 4 independent float4 loads in flight per unrolled step.
// ---------------------------------------------------------------------------
__global__ __launch_bounds__(256) void stats_kernel(const float4* __restrict__ x,
                                                    const unsigned char* __restrict__ dom,
                                                    float* __restrict__ sums,
                                                    float* __restrict__ sqs, int B) {
  const int t = threadIdx.x;
  const int tc = t & 127;
  const int rg = t >> 7;
  const int base = blockIdx.x * SROWS;
  const int rsh = 8 * rg;  // wave-uniform extra byte shift into the dom word

  float4 s0 = make_float4(0.f, 0.f, 0.f, 0.f), s1 = s0, s2 = s0, s3 = s0;
  float4 q0 = s0, q1 = s0, q2 = s0, q3 = s0;

#define ACCN(sd, qd, v)                                                        \
  do {                                                                         \
    (sd).x += (v).x; (sd).y += (v).y; (sd).z += (v).z; (sd).w += (v).w;        \
    (qd).x = fmaf((v).x, (v).x, (qd).x); (qd).y = fmaf((v).y, (v).y, (qd).y);  \
    (qd).z = fmaf((v).z, (v).z, (qd).z); (qd).w = fmaf((v).w, (v).w, (qd).w);  \
  } while (0)
#define ROWACC(v, d)                                                           \
  do {                                                                         \
    const int _d = (d); /* scalar (readfirstlane'd): s_cmp/s_cbranch only */   \
    if (_d == 0) ACCN(s0, q0, v);                                              \
    else if (_d == 1) ACCN(s1, q1, v);                                         \
    else if (_d == 2) ACCN(s2, q2, v);                                         \
    else ACCN(s3, q3, v);                                                      \
  } while (0)

  if (base + SROWS <= B) {
    const float4* xp = x + (size_t)(base + rg) * D4 + tc;
    for (int c0 = 0; c0 < SROWS; c0 += 32) {  // 32-row chunks: 2 uint4 of dom
      const uint4* dp = (const uint4*)(dom + base + c0);
      const uint4 dva = dp[0];
      const uint4 dvb = dp[1];
#pragma unroll
      for (int it = 0; it < 32; it += 8) {
        float4 v0 = xp[(size_t)(c0 + it + 0) * D4];
        float4 v1 = xp[(size_t)(c0 + it + 2) * D4];
        float4 v2 = xp[(size_t)(c0 + it + 4) * D4];
        float4 v3 = xp[(size_t)(c0 + it + 6) * D4];
        const int d0 = DOMB(it + 0);
        const int d1 = DOMB(it + 2);
        const int d2 = DOMB(it + 4);
        const int d3 = DOMB(it + 6);
        ROWACC(v0, d0);
        ROWACC(v1, d1);
        ROWACC(v2, d2);
        ROWACC(v3, d3);
      }
    }
  } else {  // tail (not hit when B % SROWS == 0)
    for (int it = 0; it < SROWS; it += 2) {
      const int r = base + it + rg;
      if (r < B) {
        const int d = __builtin_amdgcn_readfirstlane((int)dom[r]);
        float4 v = x[(size_t)r * D4 + tc];
        ROWACC(v, d);
      }
    }
  }

  // Cross-row-group reduce via LDS (stride 33 floats -> conflict-free), then
  // split the atomics: rg0 does sums, rg1 does sqs.
  __shared__ float red[128 * 33];
  float* p = &red[tc * 33];
#define STV(k, v)                                                              \
  do { p[(k)] = (v).x; p[(k) + 1] = (v).y; p[(k) + 2] = (v).z;                 \
       p[(k) + 3] = (v).w; } while (0)
  if (rg == 1) {
    STV(0, s0); STV(4, s1); STV(8, s2); STV(12, s3);
  } else {
    STV(16, q0); STV(20, q1); STV(24, q2); STV(28, q3);
  }
  __syncthreads();
#define ATV(arr, dd, v, k)                                                     \
  do {                                                                         \
    atomicAdd(&arr[(dd)*D + tc * 4 + 0], (v).x + p[(k)]);                      \
    atomicAdd(&arr[(dd)*D + tc * 4 + 1], (v).y + p[(k) + 1]);                  \
    atomicAdd(&arr[(dd)*D + tc * 4 + 2], (v).z + p[(k) + 2]);                  \
    atomicAdd(&arr[(dd)*D + tc * 4 + 3], (v).w + p[(k) + 3]);                  \
  } while (0)
  if (rg == 0) {
    ATV(sums, 0, s0, 0); ATV(sums, 1, s1, 4);
    ATV(sums, 2, s2, 8); ATV(sums, 3, s3, 12);
  } else {
    ATV(sqs, 0, q0, 16); ATV(sqs, 1, q1, 20);
    ATV(sqs, 2, q2, 24); ATV(sqs, 3, q3, 28);
  }
}

// ---------------------------------------------------------------------------
// Kernel C: finalize -> inv = gamma * rsqrt(var + eps), shift = beta - mean*inv.
// ---------------------------------------------------------------------------
__global__ __launch_bounds__(256) void fin_kernel(const float* __restrict__ sums,
                                                  const float* __restrict__ sqs,
                                                  const float* __restrict__ cnt,
                                                  const float* __restrict__ gamma,
                                                  const float* __restrict__ beta,
                                                  float* __restrict__ inv,
                                                  float* __restrict__ shf) {
  const int i = blockIdx.x * blockDim.x + threadIdx.x;
  if (i < ND * D) {
    const int d = i >> 9;  // /512
    const float c = fmaxf(cnt[d], 1.0f);
    const float m = sums[i] / c;
    const float va = sqs[i] / c - m * m;  // biased variance
    const float iv = gamma[i] * rsqrtf(va + EPSF);
    inv[i] = iv;
    shf[i] = beta[i] - m * iv;
  }
}

// ---------------------------------------------------------------------------
// Kernel D: out = fma(x, inv[dom], shift[dom]).
// inv/shf (32 KiB total) are loaded per row from global -> L1/L2 hits; no
// register table (spill risk), no arrays. dom preloaded as uint4s so the
// table-load addresses are available immediately.
// ---------------------------------------------------------------------------
__global__ __launch_bounds__(256) void norm_kernel(const float4* __restrict__ x,
                                                   const unsigned char* __restrict__ dom,
                                                   const float4* __restrict__ inv,
                                                   const float4* __restrict__ shf,
                                                   float4* __restrict__ out, int B) {
  const int t = threadIdx.x;
  const int tc = t & 127;
  const int rg = t >> 7;
  const int base = blockIdx.x * NROWS;
  const int rsh = 8 * rg;

#define FMA4(o, v, a, b)                                                       \
  do {                                                                         \
    (o).x = fmaf((v).x, (a).x, (b).x); (o).y = fmaf((v).y, (a).y, (b).y);      \
    (o).z = fmaf((v).z, (a).z, (b).z); (o).w = fmaf((v).w, (a).w, (b).w);      \
  } while (0)

  if (base + NROWS <= B) {
    const uint4* dp = (const uint4*)(dom + base);
    const uint4 dva = dp[0];
    const uint4 dvb = dp[1];
    const float4* xp = x + (size_t)(base + rg) * D4 + tc;
    float4* op = out + (size_t)(base + rg) * D4 + tc;
#pragma unroll
    for (int it = 0; it < NROWS; it += 8) {
      const int d0 = DOMB(it + 0);
      const int d1 = DOMB(it + 2);
      const int d2 = DOMB(it + 4);
      const int d3 = DOMB(it + 6);
      float4 v0 = xp[(it + 0) * D4];
      float4 v1 = xp[(it + 2) * D4];
      float4 v2 = xp[(it + 4) * D4];
      float4 v3 = xp[(it + 6) * D4];
      float4 a0 = inv[d0 * D4 + tc], b0 = shf[d0 * D4 + tc];
      float4 a1 = inv[d1 * D4 + tc], b1 = shf[d1 * D4 + tc];
      float4 a2 = inv[d2 * D4 + tc], b2 = shf[d2 * D4 + tc];
      float4 a3 = inv[d3 * D4 + tc], b3 = shf[d3 * D4 + tc];
      float4 o0, o1, o2, o3;
      FMA4(o0, v0, a0, b0);
      FMA4(o1, v1, a1, b1);
      FMA4(o2, v2, a2, b2);
      FMA4(o3, v3, a3, b3);
      op[(it + 0) * D4] = o0;
      op[(it + 2) * D4] = o1;
      op[(it + 4) * D4] = o2;
      op[(it + 6) * D4] = o3;
    }
  } else {  // tail
    for (int it = 0; it < NROWS; it += 2) {
      const int r = base + it + rg;
      if (r < B) {
        const int d = __builtin_amdgcn_readfirstlane((int)dom[r]);
        float4 v = x[(size_t)r * D4 + tc];
        float4 a = inv[d * D4 + tc], b = shf[d * D4 + tc];
        float4 o;
        FMA4(o, v, a, b);
        out[(size_t)r * D4 + tc] = o;
      }
    }
  }
}

extern "C" void kernel_launch(void* const* d_in, const int* in_sizes, int n_in,
                              void* d_out, int out_size, void* d_ws, size_t ws_size,
                              hipStream_t stream) {
  const float* x = (const float*)d_in[0];
  const float* ind = (const float*)d_in[1];
  const float* gamma = (const float*)d_in[2];
  const float* beta = (const float*)d_in[3];
  float* out = (float*)d_out;
  const int B = in_sizes[0] / D;

  // Workspace layout (bytes):
  //   [0,16)        cnt[ND]
  //   [256,8448)    sums[ND*D]
  //   [8448,16640)  sqs[ND*D]
  //   [16640,24832) inv[ND*D]
  //   [24832,33024) shf[ND*D]
  //   [33024,...)   dom[B] uint8
  char* ws = (char*)d_ws;
  float* cnt = (float*)(ws + 0);
  float* sums = (float*)(ws + 256);
  float* sqs = (float*)(ws + 256 + 8192);
  float* inv = (float*)(ws + 256 + 16384);
  float* shf = (float*)(ws + 256 + 24576);
  unsigned char* dom = (unsigned char*)(ws + 256 + 32768);

  // Accumulators must start at zero (ws is poisoned 0xAA before every call).
  (void)hipMemsetAsync(d_ws, 0, 256 + 16384, stream);

  dom_kernel<<<(B + 255) / 256, 256, 0, stream>>>((const float4*)ind, dom, cnt, B);

  stats_kernel<<<(B + SROWS - 1) / SROWS, 256, 0, stream>>>((const float4*)x, dom,
                                                            sums, sqs, B);

  fin_kernel<<<(ND * D + 255) / 256, 256, 0, stream>>>(sums, sqs, cnt, gamma, beta,
                                                       inv, shf);

  norm_kernel<<<(B + NROWS - 1) / NROWS, 256, 0, stream>>>(
      (const float4*)x, dom, (const float4*)inv, (const float4*)shf, (float4*)out, B);
}

// Round 5
// 289.034 us; speedup vs baseline: 1.5901x; 1.1095x over previous
//
#include <hip/hip_runtime.h>
#include <hip/hip_bf16.h>

#define D 512
#define D4 (D / 4)
#define ND 4
#define EPSF 1e-3f
#define SROWS 64  // rows per stats block -> 1024 blocks at B=65536
#define NROWS 32  // rows per norm block  -> 2048 blocks

// ---------------------------------------------------------------------------
// Kernel A: per-row domain id (argmax of one-hot, first-max-wins) + counts.
// ---------------------------------------------------------------------------
__global__ __launch_bounds__(256) void dom_kernel(const float4* __restrict__ ind,
                                                  unsigned char* __restrict__ dom,
                                                  float* __restrict__ cnt, int B) {
  __shared__ int lc[ND];
  const int t = threadIdx.x;
  if (t < ND) lc[t] = 0;
  __syncthreads();
  const int i = blockIdx.x * blockDim.x + t;
  if (i < B) {
    float4 v = ind[i];
    int d = 0;
    float best = v.x;
    if (v.y > best) { best = v.y; d = 1; }
    if (v.z > best) { best = v.z; d = 2; }
    if (v.w > best) { best = v.w; d = 3; }
    dom[i] = (unsigned char)d;
    atomicAdd(&lc[d], 1);
  }
  __syncthreads();
  if (t < ND && lc[t]) atomicAdd(&cnt[t], (float)lc[t]);
}

// Pick the dom word for compile-time even byte index bi in [0,32) within a
// 32-row chunk held in uint4s dva/dvb; actual row byte = bi + rg via rsh.
#define DOMW(bi)                                                               \
  ((bi) < 4 ? dva.x : (bi) < 8 ? dva.y : (bi) < 12 ? dva.z : (bi) < 16         \
   ? dva.w : (bi) < 20 ? dvb.x : (bi) < 24 ? dvb.y : (bi) < 28 ? dvb.z : dvb.w)
#define DOMB(bi)                                                               \
  __builtin_amdgcn_readfirstlane((int)((DOMW(bi) >> (8 * ((bi) & 3) + rsh)) & 3))

#define LOAD8(c)                                                               \
  v0 = xp[(size_t)((c) + 0) * D4];  v1 = xp[(size_t)((c) + 2) * D4];           \
  v2 = xp[(size_t)((c) + 4) * D4];  v3 = xp[(size_t)((c) + 6) * D4];           \
  v4 = xp[(size_t)((c) + 8) * D4];  v5 = xp[(size_t)((c) + 10) * D4];          \
  v6 = xp[(size_t)((c) + 12) * D4]; v7 = xp[(size_t)((c) + 14) * D4];

// ---------------------------------------------------------------------------
// Kernel B: per-domain per-column sum & sqsum -> per-block PARTIALS (no global
// atomics). Named float4 accumulators; __launch_bounds__(256,4) gives the
// allocator a 128-VGPR budget so nothing spills. 8 loads in flight per step.
// Partial layout (float4): partial[b*1024 + (rg?512:0) + dd*128 + tc].
// ---------------------------------------------------------------------------
__global__ __launch_bounds__(256, 4) void stats_kernel(
    const float4* __restrict__ x, const unsigned char* __restrict__ dom,
    float4* __restrict__ partial, int B) {
  const int t = threadIdx.x;
  const int tc = t & 127;
  const int rg = t >> 7;
  const int base = blockIdx.x * SROWS;
  const int rsh = 8 * rg;  // wave-uniform extra byte shift into the dom word

  float4 s0 = make_float4(0.f, 0.f, 0.f, 0.f), s1 = s0, s2 = s0, s3 = s0;
  float4 q0 = s0, q1 = s0, q2 = s0, q3 = s0;
  float4 v0, v1, v2, v3, v4, v5, v6, v7;

#define ACCN(sd, qd, v)                                                        \
  do {                                                                         \
    (sd).x += (v).x; (sd).y += (v).y; (sd).z += (v).z; (sd).w += (v).w;        \
    (qd).x = fmaf((v).x, (v).x, (qd).x); (qd).y = fmaf((v).y, (v).y, (qd).y);  \
    (qd).z = fmaf((v).z, (v).z, (qd).z); (qd).w = fmaf((v).w, (v).w, (qd).w);  \
  } while (0)
#define ROWACC(v, d)                                                           \
  do {                                                                         \
    const int _d = (d); /* scalar: s_cmp/s_cbranch only */                     \
    if (_d == 0) ACCN(s0, q0, v);                                              \
    else if (_d == 1) ACCN(s1, q1, v);                                         \
    else if (_d == 2) ACCN(s2, q2, v);                                         \
    else ACCN(s3, q3, v);                                                      \
  } while (0)
#define ACC8(it)                                                               \
  ROWACC(v0, DOMB((it) + 0));  ROWACC(v1, DOMB((it) + 2));                     \
  ROWACC(v2, DOMB((it) + 4));  ROWACC(v3, DOMB((it) + 6));                     \
  ROWACC(v4, DOMB((it) + 8));  ROWACC(v5, DOMB((it) + 10));                    \
  ROWACC(v6, DOMB((it) + 12)); ROWACC(v7, DOMB((it) + 14));

  if (base + SROWS <= B) {
    const float4* xp = x + (size_t)(base + rg) * D4 + tc;
#pragma unroll
    for (int c0 = 0; c0 < SROWS; c0 += 32) {  // 32-row chunks: 2 uint4 of dom
      const uint4* dp = (const uint4*)(dom + base + c0);
      const uint4 dva = dp[0];
      const uint4 dvb = dp[1];
      LOAD8(c0 + 0);
      ACC8(0);
      LOAD8(c0 + 16);
      ACC8(16);
    }
  } else {  // tail (not hit when B % SROWS == 0)
    for (int it = 0; it < SROWS; it += 2) {
      const int r = base + it + rg;
      if (r < B) {
        const int d = __builtin_amdgcn_readfirstlane((int)dom[r]);
        float4 v = x[(size_t)r * D4 + tc];
        ROWACC(v, d);
      }
    }
  }

  // Cross-row-group reduce via LDS (stride 33 -> conflict-free), then plain
  // coalesced partial stores: rg0 writes sums, rg1 writes sqs.
  __shared__ float red[128 * 33];
  float* p = &red[tc * 33];
#define STV(k, v)                                                              \
  do { p[(k)] = (v).x; p[(k) + 1] = (v).y; p[(k) + 2] = (v).z;                 \
       p[(k) + 3] = (v).w; } while (0)
  if (rg == 1) {
    STV(0, s0); STV(4, s1); STV(8, s2); STV(12, s3);
  } else {
    STV(16, q0); STV(20, q1); STV(24, q2); STV(28, q3);
  }
  __syncthreads();
  float4* pout = partial + (size_t)blockIdx.x * 1024 + (rg ? 512 : 0) + tc;
#define OUTV(k, v, dd)                                                         \
  do {                                                                         \
    float4 o;                                                                  \
    o.x = (v).x + p[(k)];     o.y = (v).y + p[(k) + 1];                        \
    o.z = (v).z + p[(k) + 2]; o.w = (v).w + p[(k) + 3];                        \
    pout[(dd)*128] = o;                                                        \
  } while (0)
  if (rg == 0) {
    OUTV(0, s0, 0); OUTV(4, s1, 1); OUTV(8, s2, 2); OUTV(12, s3, 3);
  } else {
    OUTV(16, q0, 0); OUTV(20, q1, 1); OUTV(24, q2, 2); OUTV(28, q3, 3);
  }
}

// ---------------------------------------------------------------------------
// Kernel B2: reduce nb per-block partials (4096 floats each) into accum[4096].
// Grid = 16 j-groups x 16 b-groups = 256 blocks; 64K atomics, depth 16.
// ---------------------------------------------------------------------------
__global__ __launch_bounds__(256) void reduce_kernel(const float* __restrict__ partial,
                                                     float* __restrict__ accum, int nb) {
  const int jg = blockIdx.x & 15;
  const int bg = blockIdx.x >> 4;
  const int nbg = gridDim.x >> 4;
  const int chunk = (nb + nbg - 1) / nbg;
  const int j = jg * 256 + threadIdx.x;
  const int b0 = bg * chunk;
  const int b1 = min(b0 + chunk, nb);
  float acc = 0.f;
  for (int b = b0; b < b1; ++b) acc += partial[(size_t)b * 4096 + j];
  atomicAdd(&accum[j], acc);
}

// ---------------------------------------------------------------------------
// Kernel C: finalize -> inv = gamma * rsqrt(var + eps), shift = beta - mean*inv.
// ---------------------------------------------------------------------------
__global__ __launch_bounds__(256) void fin_kernel(const float* __restrict__ sums,
                                                  const float* __restrict__ sqs,
                                                  const float* __restrict__ cnt,
                                                  const float* __restrict__ gamma,
                                                  const float* __restrict__ beta,
                                                  float* __restrict__ inv,
                                                  float* __restrict__ shf) {
  const int i = blockIdx.x * blockDim.x + threadIdx.x;
  if (i < ND * D) {
    const int d = i >> 9;  // /512
    const float c = fmaxf(cnt[d], 1.0f);
    const float m = sums[i] / c;
    const float va = sqs[i] / c - m * m;  // biased variance
    const float iv = gamma[i] * rsqrtf(va + EPSF);
    inv[i] = iv;
    shf[i] = beta[i] - m * iv;
  }
}

// ---------------------------------------------------------------------------
// Kernel D: out = fma(x, inv[dom], shift[dom]).
// Register-resident (inv,shf) table for all 4 domains (32 VGPRs, safe under
// the 128-VGPR budget); 8 loads in flight; scalar-branch table select.
// ---------------------------------------------------------------------------
__global__ __launch_bounds__(256, 4) void norm_kernel(const float4* __restrict__ x,
                                                      const unsigned char* __restrict__ dom,
                                                      const float4* __restrict__ inv,
                                                      const float4* __restrict__ shf,
                                                      float4* __restrict__ out, int B) {
  const int t = threadIdx.x;
  const int tc = t & 127;
  const int rg = t >> 7;
  const int base = blockIdx.x * NROWS;
  const int rsh = 8 * rg;

  const float4 A0 = inv[0 * D4 + tc], A1 = inv[1 * D4 + tc];
  const float4 A2 = inv[2 * D4 + tc], A3 = inv[3 * D4 + tc];
  const float4 B0 = shf[0 * D4 + tc], B1 = shf[1 * D4 + tc];
  const float4 B2 = shf[2 * D4 + tc], B3 = shf[3 * D4 + tc];

#define FMA4(o, v, a, b)                                                       \
  do {                                                                         \
    (o).x = fmaf((v).x, (a).x, (b).x); (o).y = fmaf((v).y, (a).y, (b).y);      \
    (o).z = fmaf((v).z, (a).z, (b).z); (o).w = fmaf((v).w, (a).w, (b).w);      \
  } while (0)
#define NROW1(v, bi)                                                           \
  do {                                                                         \
    const int _d = DOMB(bi);                                                   \
    float4 a, b;                                                               \
    if (_d == 0) { a = A0; b = B0; }                                           \
    else if (_d == 1) { a = A1; b = B1; }                                      \
    else if (_d == 2) { a = A2; b = B2; }                                      \
    else { a = A3; b = B3; }                                                   \
    float4 o;                                                                  \
    FMA4(o, v, a, b);                                                          \
    op[(size_t)(bi)*D4] = o;                                                   \
  } while (0)
#define NORM8(it)                                                              \
  NROW1(v0, (it) + 0);  NROW1(v1, (it) + 2);                                   \
  NROW1(v2, (it) + 4);  NROW1(v3, (it) + 6);                                   \
  NROW1(v4, (it) + 8);  NROW1(v5, (it) + 10);                                  \
  NROW1(v6, (it) + 12); NROW1(v7, (it) + 14);

  if (base + NROWS <= B) {
    const uint4* dp = (const uint4*)(dom + base);
    const uint4 dva = dp[0];
    const uint4 dvb = dp[1];
    const float4* xp = x + (size_t)(base + rg) * D4 + tc;
    float4* op = out + (size_t)(base + rg) * D4 + tc;
    float4 v0, v1, v2, v3, v4, v5, v6, v7;
    LOAD8(0);
    NORM8(0);
    LOAD8(16);
    NORM8(16);
  } else {  // tail
    for (int it = 0; it < NROWS; it += 2) {
      const int r = base + it + rg;
      if (r < B) {
        const int d = __builtin_amdgcn_readfirstlane((int)dom[r]);
        float4 v = x[(size_t)r * D4 + tc];
        float4 a = inv[d * D4 + tc], b = shf[d * D4 + tc];
        float4 o;
        FMA4(o, v, a, b);
        out[(size_t)r * D4 + tc] = o;
      }
    }
  }
}

extern "C" void kernel_launch(void* const* d_in, const int* in_sizes, int n_in,
                              void* d_out, int out_size, void* d_ws, size_t ws_size,
                              hipStream_t stream) {
  const float* x = (const float*)d_in[0];
  const float* ind = (const float*)d_in[1];
  const float* gamma = (const float*)d_in[2];
  const float* beta = (const float*)d_in[3];
  float* out = (float*)d_out;
  const int B = in_sizes[0] / D;

  // Workspace layout (bytes):
  //   [0,16)        cnt[ND]
  //   [256,16640)   accum[4096]  (sums[2048] || sqs[2048])
  //   [16640,24832) inv[ND*D]
  //   [24832,33024) shf[ND*D]
  //   [33024,...)   dom[B] uint8
  // Per-block stats partials (nblk_s * 16 KiB) live in d_out, which norm_kernel
  // fully overwrites afterwards (same stream -> ordered).
  char* ws = (char*)d_ws;
  float* cnt = (float*)(ws + 0);
  float* accum = (float*)(ws + 256);
  float* inv = (float*)(ws + 256 + 16384);
  float* shf = (float*)(ws + 256 + 24576);
  unsigned char* dom = (unsigned char*)(ws + 256 + 32768);

  // cnt + accum must start at zero (ws is poisoned 0xAA before every call).
  (void)hipMemsetAsync(d_ws, 0, 256 + 16384, stream);

  dom_kernel<<<(B + 255) / 256, 256, 0, stream>>>((const float4*)ind, dom, cnt, B);

  const int nblk_s = (B + SROWS - 1) / SROWS;  // 1024 at B=65536
  stats_kernel<<<nblk_s, 256, 0, stream>>>((const float4*)x, dom, (float4*)out, B);

  reduce_kernel<<<256, 256, 0, stream>>>((const float*)out, accum, nblk_s);

  fin_kernel<<<(ND * D + 255) / 256, 256, 0, stream>>>(accum, accum + 2048, cnt,
                                                       gamma, beta, inv, shf);

  norm_kernel<<<(B + NROWS - 1) / NROWS, 256, 0, stream>>>(
      (const float4*)x, dom, (const float4*)inv, (const float4*)shf, (float4*)out, B);
}